// Round 22
// baseline (73.531 us; speedup 1.0000x reference)
//
#include <hip/hip_runtime.h>
#include <hip/hip_bf16.h>

#define NB 32768
#define ND 512
#define NS 128
#define NE 8
#define TPE 160  // 32-row tiles per expert (covers cnt up to 5120)

typedef __attribute__((ext_vector_type(8))) short bf16x8;
typedef __attribute__((ext_vector_type(4))) float f32x4;

__device__ __forceinline__ unsigned short f2b(float f) {
  union { __hip_bfloat16 h; unsigned short u; } cv;
  cv.h = __float2bfloat16(f);
  return cv.u;
}

__device__ __forceinline__ bf16x8 relu_cvt8v(float4 a, float4 b) {
  bf16x8 r;
  r[0] = (short)f2b(fmaxf(a.x, 0.f)); r[1] = (short)f2b(fmaxf(a.y, 0.f));
  r[2] = (short)f2b(fmaxf(a.z, 0.f)); r[3] = (short)f2b(fmaxf(a.w, 0.f));
  r[4] = (short)f2b(fmaxf(b.x, 0.f)); r[5] = (short)f2b(fmaxf(b.y, 0.f));
  r[6] = (short)f2b(fmaxf(b.z, 0.f)); r[7] = (short)f2b(fmaxf(b.w, 0.f));
  return r;
}

__device__ __forceinline__ void gload16(const void* gsrc, void* ldst) {
  __builtin_amdgcn_global_load_lds(
      (const __attribute__((address_space(1))) unsigned int*)gsrc,
      (__attribute__((address_space(3))) unsigned int*)ldst, 16, 0, 0);
}

// counted-vmcnt phase barriers (T4): memory clobber pins VMEM issue order.
#define BARV2  asm volatile("s_waitcnt vmcnt(2)\n\ts_barrier" ::: "memory")
#define BARV0  asm volatile("s_waitcnt vmcnt(0)\n\ts_barrier" ::: "memory")
#define BARL   asm volatile("s_waitcnt lgkmcnt(0)\n\ts_barrier" ::: "memory")
#define BARV2L asm volatile("s_waitcnt vmcnt(2) lgkmcnt(0)\n\ts_barrier" ::: "memory")
#define CFENCE asm volatile("" ::: "memory")

__global__ void zero_counts_k(int* counts) {
  if (threadIdx.x < NE) counts[threadIdx.x] = 0;
}

__global__ void bin_rows_k(const int* __restrict__ yidx, int* __restrict__ counts,
                           int* __restrict__ bucket) {
  __shared__ int lcnt[NE];
  __shared__ int lbase[NE];
  int tid = threadIdx.x;
  if (tid < NE) lcnt[tid] = 0;
  __syncthreads();
  int b = blockIdx.x * blockDim.x + tid;
  int e = yidx[b];
  int pos = atomicAdd(&lcnt[e], 1);
  __syncthreads();
  if (tid < NE) lbase[tid] = atomicAdd(&counts[tid], lcnt[tid]);
  __syncthreads();
  bucket[e * NB + lbase[e] + pos] = b;
}

// [R][C] f32 -> [C][R] bf16, XOR pre-swizzle within 64-short groups so a
// LINEAR global_load_lds copy lands bank-swizzled in LDS.
__global__ void transpose_cvt_k(const float* __restrict__ in,
                                unsigned short* __restrict__ out, int R, int C) {
  __shared__ float lt[32][33];
  int tpm = (R >> 5) * (C >> 5);
  int mat = blockIdx.x / tpm;
  int rem = blockIdx.x % tpm;
  int tcn = C >> 5;
  int tr = rem / tcn, tc = rem % tcn;
  const float* mi = in + (size_t)mat * R * C;
  unsigned short* mo = out + (size_t)mat * R * C;
  int r = threadIdx.x >> 5, c = threadIdx.x & 31;
#pragma unroll
  for (int i = 0; i < 4; ++i) {
    int rr = r + i * 8;
    lt[rr][c] = mi[(size_t)(tr * 32 + rr) * C + tc * 32 + c];
  }
  __syncthreads();
#pragma unroll
  for (int i = 0; i < 4; ++i) {
    int rr = r + i * 8;
    int orow = tc * 32 + rr;
    int d = tr * 32 + c;
    int ocol = (d & ~63) | ((d & 63) ^ ((orow & 7) << 3));
    mo[(size_t)orow * R + ocol] = f2b(lt[c][rr]);
  }
}

// ---- Fused MoE, TM=32: x LDS-staged, stage-2 reg-accum, burst epilogue ----
#define M1STAGE(c)                                                        \
  do {                                                                    \
    gload16(g0 + (c) * 128, (char*)wt[(c) % 3] + p0 * 16);                \
    gload16(g1 + (c) * 128, (char*)wt[(c) % 3] + p1 * 16);                \
  } while (0)

#define M2STAGE(c)                                                           \
  do {                                                                       \
    gload16(w2e + (c) * 16384 + p0 * 16, (char*)wt[(c) % 3] + p0 * 16);      \
    gload16(w2e + (c) * 16384 + p1 * 16, (char*)wt[(c) % 3] + p1 * 16);      \
  } while (0)

// stage-1 phase: pure {<=2 DMA + LDS reads + 4 MFMA}; depth-2 ledger BARV2.
// Phase 7 prefetches W2 chunk 0 into wt[0] (free slot; wt[0] last read ph6).
#define M1_ITER(c)                                                             \
  do {                                                                         \
    if ((c) <= 5) { M1STAGE((c) + 2); }                                        \
    if ((c) == 7) { M2STAGE(0); }                                               \
    bf16x8 a0 = *(const bf16x8*)(xtb + arow * 1024 +                           \
                                 (((c) * 128 + l4 * 16) ^ arsw));              \
    bf16x8 a1 = *(const bf16x8*)(xtb + arow * 1024 +                           \
                                 (((c) * 128 + 64 + l4 * 16) ^ arsw));         \
    const unsigned short* wb = wt[(c) % 3];                                    \
    __builtin_amdgcn_s_setprio(1);                                             \
    _Pragma("unroll") for (int nt = 0; nt < 2; ++nt) {                         \
      int n = ng * 32 + nt * 16 + l15;                                         \
      int sw = (n & 7) << 3;                                                   \
      bf16x8 b0 = *(const bf16x8*)&wb[n * 64 + ((l4 * 8) ^ sw)];               \
      bf16x8 b1v = *(const bf16x8*)&wb[n * 64 + ((32 + l4 * 8) ^ sw)];         \
      acc[nt] = __builtin_amdgcn_mfma_f32_16x16x32_bf16(a0, b0, acc[nt], 0, 0, 0);  \
      acc[nt] = __builtin_amdgcn_mfma_f32_16x16x32_bf16(a1, b1v, acc[nt], 0, 0, 0); \
    }                                                                          \
    __builtin_amdgcn_s_setprio(0);                                             \
    if ((c) <= 5) { BARV2; } else if ((c) == 6) { BARV0; }                     \
  } while (0)

// stage-2 phase: pure {<=2 DMA + 4 MFMA}; acc2[c] statically indexed
// (rule #20); trivial depth-2 ledger BARV2/BARV0.
#define M2_ITER(c)                                                            \
  do {                                                                        \
    if ((c) <= 5) { M2STAGE((c) + 2); }                                       \
    const unsigned short* wb = wt[(c) % 3];                                   \
    __builtin_amdgcn_s_setprio(1);                                            \
    _Pragma("unroll") for (int kk = 0; kk < 4; ++kk) {                        \
      int dl0 = ng * 16 + l15;                                                \
      int sw0 = (dl0 & 7) << 3;                                               \
      bf16x8 bv0 = *(const bf16x8*)&wb[dl0 * 128 + ((kk * 32 + l4 * 8) ^ sw0)]; \
      acc2[c] = __builtin_amdgcn_mfma_f32_16x16x32_bf16(ha[kk], bv0,          \
                                                        acc2[c], 0, 0, 0);    \
    }                                                                         \
    __builtin_amdgcn_s_setprio(0);                                            \
    if ((c) <= 5) { BARV2; } else if ((c) == 6) { BARV0; }                    \
  } while (0)

__launch_bounds__(512, 4)
__global__ void moe_f(const float* __restrict__ x, const float* __restrict__ z,
                      const float* __restrict__ b1, const float* __restrict__ b2,
                      const unsigned short* __restrict__ w1sw,
                      const unsigned short* __restrict__ w2sw,
                      const int* __restrict__ counts, const int* __restrict__ bucket,
                      float* __restrict__ out) {
  __shared__ unsigned short wt[3][8192];  // 48 KB; wt[2] doubles as H exchange
  __shared__ unsigned short xt[32][512];  // 32 KB x tile, XOR-swizzled rows
  char* htb = (char*)wt[2];               // ht[32][128] bf16, XOR-swizzled (8 KB)
  char* xtb = (char*)xt;
  int e = blockIdx.x & 7;  // XCD pin
  int t = blockIdx.x >> 3;
  int cnt = counts[e];
  if (t * 32 >= cnt) return;  // uniform exit before any barrier
  int tid = threadIdx.x, w = tid >> 6, lane = tid & 63;
  int l15 = lane & 15, l4 = lane >> 4;
  int rg = w >> 2, ng = w & 3;

  // ---- x staging: wave w stages rows w*4..w*4+4, one 2KB burst per row ----
#pragma unroll
  for (int j = 0; j < 4; ++j) {
    int row = w * 4 + j;
    int pos = t * 32 + row;
    int ps = (pos < cnt) ? pos : (cnt - 1);
    int rid = bucket[e * NB + ps];
    const float* xp = x + (size_t)rid * ND + lane * 8;
    float4 a = *(const float4*)xp;
    float4 b = *(const float4*)(xp + 4);
    bf16x8 v = relu_cvt8v(a, b);
    *(bf16x8*)(xtb + row * 1024 + ((lane * 16) ^ ((row & 7) << 4))) = v;
  }

  const char* w1e = (const char*)w1sw + (size_t)e * NS * ND * 2;
  const char* w2e = (const char*)w2sw + (size_t)e * ND * NS * 2;
  int p0 = tid, p1 = tid + 512;
  const char* g0 = w1e + (p0 >> 3) * 1024 + (p0 & 7) * 16;
  const char* g1 = w1e + (p1 >> 3) * 1024 + (p1 & 7) * 16;

  // prologue: W1 chunks 0,1
  M1STAGE(0);
  CFENCE;                 // S(0) older than S(1)
  M1STAGE(1);
  BARV2L;                 // retires S(0); xt ds_writes drained; S(1) in flight

  f32x4 acc[2];
  acc[0] = (f32x4){0.f, 0.f, 0.f, 0.f};
  acc[1] = (f32x4){0.f, 0.f, 0.f, 0.f};
  int arow = rg * 16 + l15;
  int arsw = (arow & 7) << 4;

  // ---------------- stage 1 (phase 7 prefetches W2 chunk 0) ----------------
  M1_ITER(0); M1_ITER(1); M1_ITER(2); M1_ITER(3);
  M1_ITER(4); M1_ITER(5); M1_ITER(6); M1_ITER(7);
  // after phase 6's BARV0 all waves are past all W1 reads; phase 7 reads wt[1]

  // ------- transition: H -> wt[2] (swizzled), row state, W2(1) ------------
#pragma unroll
  for (int nt = 0; nt < 2; ++nt) {
    int col = ng * 32 + nt * 16 + l15;
    float bias = b1[e * NS + col];
#pragma unroll
    for (int r = 0; r < 4; ++r) {
      int row = rg * 16 + l4 * 4 + r;
      int off = (row * 256 + col * 2) ^ ((row & 7) << 4);
      *(unsigned short*)(htb + off) = f2b(fmaxf(acc[nt][r] + bias, 0.f));
    }
  }

  int orow[4];
  bool valid[4];
  float zr[4];
#pragma unroll
  for (int r = 0; r < 4; ++r) {
    int pos = t * 32 + rg * 16 + l4 * 4 + r;
    valid[r] = (pos < cnt);
    int ps = valid[r] ? pos : (cnt - 1);
    orow[r] = bucket[e * NB + ps];
    zr[r] = z[orow[r]];
  }

  BARL;                   // ht visible; phase-7 wt[1] readers all done
  M2STAGE(1);             // wt[1]: now safe (W2(0) already in flight to wt[0])

  bf16x8 ha[4];
#pragma unroll
  for (int kk = 0; kk < 4; ++kk) {
    int row = rg * 16 + l15;
    int off = (row * 256 + (kk * 32 + l4 * 8) * 2) ^ ((row & 7) << 4);
    ha[kk] = *(const bf16x8*)(htb + off);
  }
  BARV2L;                 // retires S2(0)+rowstate; keeps S2(1); ha drained

  // ---------------- stage 2: pure MFMA phases, acc in registers ----------
  f32x4 acc2[8];
#pragma unroll
  for (int i = 0; i < 8; ++i) acc2[i] = (f32x4){0.f, 0.f, 0.f, 0.f};

  M2_ITER(0); M2_ITER(1); M2_ITER(2); M2_ITER(3);
  M2_ITER(4); M2_ITER(5); M2_ITER(6); M2_ITER(7);

  // ---------------- burst epilogue: no barriers, full MLP ----------------
#pragma unroll
  for (int c = 0; c < 8; ++c) {
    int d0 = c * 64 + ng * 16 + l15;
    float bias0 = b2[e * ND + d0];
#pragma unroll
    for (int r = 0; r < 4; ++r) {
      if (valid[r]) {
        size_t o0 = (size_t)orow[r] * ND + d0;
        out[o0] = x[o0] + (acc2[c][r] + bias0) * zr[r];
      }
    }
  }
}

extern "C" void kernel_launch(void* const* d_in, const int* in_sizes, int n_in,
                              void* d_out, int out_size, void* d_ws, size_t ws_size,
                              hipStream_t stream) {
  const float* x = (const float*)d_in[0];
  const int* yidx = (const int*)d_in[1];
  // d_in[2] = y_hard (unused by reference)
  const float* z = (const float*)d_in[3];
  const float* W1 = (const float*)d_in[4];
  const float* b1 = (const float*)d_in[5];
  const float* W2 = (const float*)d_in[6];
  const float* b2 = (const float*)d_in[7];
  float* out = (float*)d_out;

  char* ws = (char*)d_ws;
  int* counts = (int*)ws;                     // 32 B
  int* bucket = (int*)(ws + 256);             // 1 MB
  size_t off = 256 + (size_t)NE * NB * 4;
  unsigned short* w1sw = (unsigned short*)(ws + off);  // 1 MB (swizzled)
  off += (size_t)NE * NS * ND * 2;
  unsigned short* w2sw = (unsigned short*)(ws + off);  // 1 MB (swizzled)

  zero_counts_k<<<1, 64, 0, stream>>>(counts);
  bin_rows_k<<<NB / 1024, 1024, 0, stream>>>(yidx, counts, bucket);
  // W1 [E][D][S] -> [E][S][D] pre-swizzled; W2 [E][S][D] -> [E][D][S] pre-swizzled
  transpose_cvt_k<<<NE * (ND / 32) * (NS / 32), 256, 0, stream>>>(W1, w1sw, ND, NS);
  transpose_cvt_k<<<NE * (NS / 32) * (ND / 32), 256, 0, stream>>>(W2, w2sw, NS, ND);
  moe_f<<<NE * TPE, 512, 0, stream>>>(x, z, b1, b2, w1sw, w2sw, counts, bucket, out);
}

// Round 23
// 59.212 us; speedup vs baseline: 1.2418x; 1.2418x over previous
//
#include <hip/hip_runtime.h>
#include <hip/hip_bf16.h>

#define NB 32768
#define ND 512
#define NS 128
#define NE 8
#define TPE 160  // 32-row tiles per expert (covers cnt up to 5120)

typedef __attribute__((ext_vector_type(8))) short bf16x8;
typedef __attribute__((ext_vector_type(4))) float f32x4;

__device__ __forceinline__ unsigned short f2b(float f) {
  union { __hip_bfloat16 h; unsigned short u; } cv;
  cv.h = __float2bfloat16(f);
  return cv.u;
}

__device__ __forceinline__ bf16x8 relu_cvt8v(float4 a, float4 b) {
  bf16x8 r;
  r[0] = (short)f2b(fmaxf(a.x, 0.f)); r[1] = (short)f2b(fmaxf(a.y, 0.f));
  r[2] = (short)f2b(fmaxf(a.z, 0.f)); r[3] = (short)f2b(fmaxf(a.w, 0.f));
  r[4] = (short)f2b(fmaxf(b.x, 0.f)); r[5] = (short)f2b(fmaxf(b.y, 0.f));
  r[6] = (short)f2b(fmaxf(b.z, 0.f)); r[7] = (short)f2b(fmaxf(b.w, 0.f));
  return r;
}

__device__ __forceinline__ void gload16(const void* gsrc, void* ldst) {
  __builtin_amdgcn_global_load_lds(
      (const __attribute__((address_space(1))) unsigned int*)gsrc,
      (__attribute__((address_space(3))) unsigned int*)ldst, 16, 0, 0);
}

// counted-vmcnt phase barriers (T4): memory clobber pins VMEM issue order.
#define BARV7  asm volatile("s_waitcnt vmcnt(7)\n\ts_barrier" ::: "memory")
#define BARV5  asm volatile("s_waitcnt vmcnt(5)\n\ts_barrier" ::: "memory")
#define BARV2  asm volatile("s_waitcnt vmcnt(2)\n\ts_barrier" ::: "memory")
#define BARV0  asm volatile("s_waitcnt vmcnt(0)\n\ts_barrier" ::: "memory")
#define BARL   asm volatile("s_waitcnt lgkmcnt(0)\n\ts_barrier" ::: "memory")
#define BARV2L asm volatile("s_waitcnt vmcnt(2) lgkmcnt(0)\n\ts_barrier" ::: "memory")
#define CFENCE asm volatile("" ::: "memory")

__global__ void zero_counts_k(int* counts) {
  if (threadIdx.x < NE) counts[threadIdx.x] = 0;
}

__global__ void bin_rows_k(const int* __restrict__ yidx, int* __restrict__ counts,
                           int* __restrict__ bucket) {
  __shared__ int lcnt[NE];
  __shared__ int lbase[NE];
  int tid = threadIdx.x;
  if (tid < NE) lcnt[tid] = 0;
  __syncthreads();
  int b = blockIdx.x * blockDim.x + tid;
  int e = yidx[b];
  int pos = atomicAdd(&lcnt[e], 1);
  __syncthreads();
  if (tid < NE) lbase[tid] = atomicAdd(&counts[tid], lcnt[tid]);
  __syncthreads();
  bucket[e * NB + lbase[e] + pos] = b;
}

// [R][C] f32 -> [C][R] bf16, XOR pre-swizzle within 64-short groups so a
// LINEAR global_load_lds copy lands bank-swizzled in LDS.
__global__ void transpose_cvt_k(const float* __restrict__ in,
                                unsigned short* __restrict__ out, int R, int C) {
  __shared__ float lt[32][33];
  int tpm = (R >> 5) * (C >> 5);
  int mat = blockIdx.x / tpm;
  int rem = blockIdx.x % tpm;
  int tcn = C >> 5;
  int tr = rem / tcn, tc = rem % tcn;
  const float* mi = in + (size_t)mat * R * C;
  unsigned short* mo = out + (size_t)mat * R * C;
  int r = threadIdx.x >> 5, c = threadIdx.x & 31;
#pragma unroll
  for (int i = 0; i < 4; ++i) {
    int rr = r + i * 8;
    lt[rr][c] = mi[(size_t)(tr * 32 + rr) * C + tc * 32 + c];
  }
  __syncthreads();
#pragma unroll
  for (int i = 0; i < 4; ++i) {
    int rr = r + i * 8;
    int orow = tc * 32 + rr;
    int d = tr * 32 + c;
    int ocol = (d & ~63) | ((d & 63) ^ ((orow & 7) << 3));
    mo[(size_t)orow * R + ocol] = f2b(lt[c][rr]);
  }
}

// ---- Fused MoE, TM=32: x LDS-staged once (row bursts), 80 KB -> 2 blk/CU ----
// 8 waves = 2 row-groups (rg) x 4 col-groups (ng).
#define M1STAGE(c)                                                        \
  do {                                                                    \
    gload16(g0 + (c) * 128, (char*)wt[(c) % 3] + p0 * 16);                \
    gload16(g1 + (c) * 128, (char*)wt[(c) % 3] + p1 * 16);                \
  } while (0)

// stage-1 phase: pure {2 DMA + LDS reads + 4 MFMA}; ledger: depth-2, BARV2.
#define M1_ITER(c)                                                             \
  do {                                                                         \
    if ((c) <= 5) { M1STAGE((c) + 2); }                                        \
    bf16x8 a0 = *(const bf16x8*)(xtb + arow * 1024 +                           \
                                 (((c) * 128 + l4 * 16) ^ arsw));              \
    bf16x8 a1 = *(const bf16x8*)(xtb + arow * 1024 +                           \
                                 (((c) * 128 + 64 + l4 * 16) ^ arsw));         \
    const unsigned short* wb = wt[(c) % 3];                                    \
    __builtin_amdgcn_s_setprio(1);                                             \
    _Pragma("unroll") for (int nt = 0; nt < 2; ++nt) {                         \
      int n = ng * 32 + nt * 16 + l15;                                         \
      int sw = (n & 7) << 3;                                                   \
      bf16x8 b0 = *(const bf16x8*)&wb[n * 64 + ((l4 * 8) ^ sw)];               \
      bf16x8 b1v = *(const bf16x8*)&wb[n * 64 + ((32 + l4 * 8) ^ sw)];         \
      acc[nt] = __builtin_amdgcn_mfma_f32_16x16x32_bf16(a0, b0, acc[nt], 0, 0, 0);  \
      acc[nt] = __builtin_amdgcn_mfma_f32_16x16x32_bf16(a1, b1v, acc[nt], 0, 0, 0); \
    }                                                                          \
    __builtin_amdgcn_s_setprio(0);                                             \
    if ((c) <= 5) { BARV2; } else if ((c) == 6) { BARV0; }                     \
  } while (0)

#define M2STAGE(c)                                                           \
  do {                                                                       \
    gload16(w2e + (c) * 16384 + p0 * 16, (char*)wt[(c) % 3] + p0 * 16);      \
    gload16(w2e + (c) * 16384 + p1 * 16, (char*)wt[(c) % 3] + p1 * 16);      \
  } while (0)

// stage-2 phase: 2 DMA + 4 x + 1 b2 + 4 stores; in-phase loads are consumed
// in-phase (latency hides under the DMA wait); steady barrier BARV7.
#define M2_ITER(c)                                                            \
  do {                                                                        \
    if ((c) <= 5) { M2STAGE((c) + 2); }                                       \
    float xe0[4];                                                             \
    int d0 = (c) * 64 + ng * 16 + l15;                                        \
    _Pragma("unroll") for (int r = 0; r < 4; ++r)                             \
      xe0[r] = x[(size_t)orow[r] * ND + d0];                                  \
    float bias0 = b2[e * ND + d0];                                            \
    const unsigned short* wb = wt[(c) % 3];                                   \
    f32x4 acc0 = (f32x4){0.f, 0.f, 0.f, 0.f};                                 \
    __builtin_amdgcn_s_setprio(1);                                            \
    _Pragma("unroll") for (int kk = 0; kk < 4; ++kk) {                        \
      int dl0 = ng * 16 + l15;                                                \
      int sw0 = (dl0 & 7) << 3;                                               \
      bf16x8 bv0 = *(const bf16x8*)&wb[dl0 * 128 + ((kk * 32 + l4 * 8) ^ sw0)]; \
      acc0 = __builtin_amdgcn_mfma_f32_16x16x32_bf16(ha[kk], bv0, acc0, 0, 0, 0); \
    }                                                                         \
    __builtin_amdgcn_s_setprio(0);                                            \
    _Pragma("unroll") for (int r = 0; r < 4; ++r) {                           \
      float r0 = xe0[r] + (acc0[r] + bias0) * zr[r];                          \
      float* p0s = valid[r] ? (out + (size_t)orow[r] * ND + d0) : (osink + tid); \
      *p0s = r0;                                                              \
    }                                                                         \
    if ((c) <= 5) { BARV7; } else if ((c) == 6) { BARV5; }                    \
  } while (0)

__launch_bounds__(512, 4)
__global__ void moe_f(const float* __restrict__ x, const float* __restrict__ z,
                      const float* __restrict__ b1, const float* __restrict__ b2,
                      const unsigned short* __restrict__ w1sw,
                      const unsigned short* __restrict__ w2sw,
                      const int* __restrict__ counts, const int* __restrict__ bucket,
                      float* __restrict__ out, float* __restrict__ osink) {
  __shared__ unsigned short wt[3][8192];  // 48 KB; wt[2] doubles as H exchange
  __shared__ unsigned short xt[32][512];  // 32 KB x tile, XOR-swizzled rows
  char* htb = (char*)wt[2];               // ht[32][128] bf16, XOR-swizzled (8 KB)
  char* xtb = (char*)xt;
  int e = blockIdx.x & 7;  // XCD pin
  int t = blockIdx.x >> 3;
  int cnt = counts[e];
  if (t * 32 >= cnt) return;  // uniform exit before any barrier
  int tid = threadIdx.x, w = tid >> 6, lane = tid & 63;
  int l15 = lane & 15, l4 = lane >> 4;
  int rg = w >> 2, ng = w & 3;

  // ---- x staging: wave w stages rows w*4..w*4+4, one 2KB burst per row ----
#pragma unroll
  for (int j = 0; j < 4; ++j) {
    int row = w * 4 + j;
    int pos = t * 32 + row;
    int ps = (pos < cnt) ? pos : (cnt - 1);
    int rid = bucket[e * NB + ps];
    const float* xp = x + (size_t)rid * ND + lane * 8;
    float4 a = *(const float4*)xp;
    float4 b = *(const float4*)(xp + 4);
    bf16x8 v = relu_cvt8v(a, b);
    *(bf16x8*)(xtb + row * 1024 + ((lane * 16) ^ ((row & 7) << 4))) = v;
  }

  const char* w1e = (const char*)w1sw + (size_t)e * NS * ND * 2;
  const char* w2e = (const char*)w2sw + (size_t)e * ND * NS * 2;
  int p0 = tid, p1 = tid + 512;
  const char* g0 = w1e + (p0 >> 3) * 1024 + (p0 & 7) * 16;
  const char* g1 = w1e + (p1 >> 3) * 1024 + (p1 & 7) * 16;

  // prologue: W1 chunks 0,1 (x loads already retired by ds_write waits)
  M1STAGE(0);
  CFENCE;                 // S(0) older than S(1)
  M1STAGE(1);
  BARV2L;                 // retires S(0); xt ds_writes drained; S(1) in flight

  f32x4 acc[2];
  acc[0] = (f32x4){0.f, 0.f, 0.f, 0.f};
  acc[1] = (f32x4){0.f, 0.f, 0.f, 0.f};
  int arow = rg * 16 + l15;
  int arsw = (arow & 7) << 4;

  // ---------------- stage 1 ----------------
  M1_ITER(0); M1_ITER(1); M1_ITER(2); M1_ITER(3);
  M1_ITER(4); M1_ITER(5); M1_ITER(6); M1_ITER(7);
  // phase 7 has no end barrier; wt[2] free (all waves past phase-6 BARV0)

  // ------- transition: H -> wt[2] (swizzled), row state, W2 prologue -------
#pragma unroll
  for (int nt = 0; nt < 2; ++nt) {
    int col = ng * 32 + nt * 16 + l15;
    float bias = b1[e * NS + col];
#pragma unroll
    for (int r = 0; r < 4; ++r) {
      int row = rg * 16 + l4 * 4 + r;
      int off = (row * 256 + col * 2) ^ ((row & 7) << 4);
      *(unsigned short*)(htb + off) = f2b(fmaxf(acc[nt][r] + bias, 0.f));
    }
  }

  int orow[4];
  bool valid[4];
  float zr[4];
#pragma unroll
  for (int r = 0; r < 4; ++r) {
    int pos = t * 32 + rg * 16 + l4 * 4 + r;
    valid[r] = (pos < cnt);
    int ps = valid[r] ? pos : (cnt - 1);
    orow[r] = bucket[e * NB + ps];
    zr[r] = z[orow[r]];
  }

  M2STAGE(0);             // wt[0]: safe, all waves past phase-6 barrier
  BARL;                   // ht visible; phase-7 wt[1] readers done
  M2STAGE(1);             // wt[1]: now safe

  bf16x8 ha[4];
#pragma unroll
  for (int kk = 0; kk < 4; ++kk) {
    int row = rg * 16 + l15;
    int off = (row * 256 + (kk * 32 + l4 * 8) * 2) ^ ((row & 7) << 4);
    ha[kk] = *(const bf16x8*)(htb + off);
  }
  BARV2L;                 // retires S2(0)+older; ha reads drained before S2(2)

  // ---------------- stage 2 + fused epilogue ----------------
  M2_ITER(0); M2_ITER(1); M2_ITER(2); M2_ITER(3);
  M2_ITER(4); M2_ITER(5); M2_ITER(6); M2_ITER(7);
}

extern "C" void kernel_launch(void* const* d_in, const int* in_sizes, int n_in,
                              void* d_out, int out_size, void* d_ws, size_t ws_size,
                              hipStream_t stream) {
  const float* x = (const float*)d_in[0];
  const int* yidx = (const int*)d_in[1];
  // d_in[2] = y_hard (unused by reference)
  const float* z = (const float*)d_in[3];
  const float* W1 = (const float*)d_in[4];
  const float* b1 = (const float*)d_in[5];
  const float* W2 = (const float*)d_in[6];
  const float* b2 = (const float*)d_in[7];
  float* out = (float*)d_out;

  char* ws = (char*)d_ws;
  int* counts = (int*)ws;                     // 32 B
  int* bucket = (int*)(ws + 256);             // 1 MB
  size_t off = 256 + (size_t)NE * NB * 4;
  unsigned short* w1sw = (unsigned short*)(ws + off);  // 1 MB (swizzled)
  off += (size_t)NE * NS * ND * 2;
  unsigned short* w2sw = (unsigned short*)(ws + off);  // 1 MB (swizzled)
  off += (size_t)NE * ND * NS * 2;
  float* osink = (float*)(ws + off);          // 4 KB dummy store sink

  zero_counts_k<<<1, 64, 0, stream>>>(counts);
  bin_rows_k<<<NB / 1024, 1024, 0, stream>>>(yidx, counts, bucket);
  // W1 [E][D][S] -> [E][S][D] pre-swizzled; W2 [E][S][D] -> [E][D][S] pre-swizzled
  transpose_cvt_k<<<NE * (ND / 32) * (NS / 32), 256, 0, stream>>>(W1, w1sw, ND, NS);
  transpose_cvt_k<<<NE * (NS / 32) * (ND / 32), 256, 0, stream>>>(W2, w2sw, NS, ND);
  moe_f<<<NE * TPE, 512, 0, stream>>>(x, z, b1, b2, w1sw, w2sw, counts, bucket,
                                      out, osink);
}